// Round 4
// baseline (592.142 us; speedup 1.0000x reference)
//
#include <hip/hip_runtime.h>
#include <cstdint>

// Sparse BasicBlock via bf16 MFMA implicit GEMM — zero-LDS, zero-barrier.
//   u   = mask * vector * relu(bn1(conv1(x * mask_dilate)))
//   out = relu(x + mask * bn2(conv2(u)))
// Activations live in a padded ci8-planar layout [img][ci8][58][66][8ci] bf16
// (1-px zero border in y and x, so the 3x3 taps need no edge branches).
// Both MFMA operands are read DIRECTLY from global (L1/L2-cached) as
// contiguous 16B/lane fragments: A = weights [chunk][tap][half][256co][8ci],
// B = pixels. mfma(wf, pf): D col = pixel (lane&31), row = co (reg-mapped).
// Wave tile: 64 co x 128 px (2 rows x 64 cols); block = 4 waves = 128 co x
// 4 rows x 64 px. No __shared__, no __syncthreads => no races, waves
// self-pipeline loads under MFMA. Images processed in 2 groups of 16 to
// keep workspace at ~65 MB.

#define EPS 1e-5f

constexpr int Cc = 256, Hh = 56, Ww = 56, HW = 3136;
constexpr int NG = 16;                 // images per group
constexpr int PH = 58, PW = 66;        // padded plane dims
constexpr int PS = PH * PW * 8;        // 30624 elements per (img, ci8) plane
constexpr int IPS = 32 * PS;           // 979,968 elements per image
constexpr int WP_EL = 16 * 9 * 2 * 256 * 8;   // 589,824 per conv
constexpr int PACK_POS = NG * 32 * PH * PW;   // 1,959,936 positions

typedef __bf16 bf16x8 __attribute__((ext_vector_type(8)));
typedef __bf16 bf16x4 __attribute__((ext_vector_type(4)));
typedef float  f32x16 __attribute__((ext_vector_type(16)));

// ---- pack x*mask_dilate -> padded planar bf16 [il][ci8][58][66][8] ----
__global__ void pack_xm2(const float* __restrict__ x, const float* __restrict__ md,
                         __bf16* __restrict__ dst, int img0) {
    int pos = blockIdx.x * 256 + threadIdx.x;        // < PACK_POS
    int xx = pos % PW; int t = pos / PW;
    int yy = t % PH;  t /= PH;
    int ci8 = t & 31; int il = t >> 5;
    int img = img0 + il;
    bf16x8 v = {};
    int xi = xx - 1, yi = yy - 1;
    if ((unsigned)xi < 56u && (unsigned)yi < 56u) {
        float mdv = md[(size_t)img * HW + yi * 56 + xi];
        #pragma unroll
        for (int j = 0; j < 8; ++j)
            v[j] = (__bf16)(x[((size_t)(img * Cc) + ci8 * 8 + j) * HW + yi * 56 + xi] * mdv);
    }
    *(bf16x8*)&dst[(size_t)pos * 8] = v;
}

// ---- zero-fill u2 (borders must be zero; interior overwritten by conv1) ----
__global__ void zero_fill(__bf16* __restrict__ dst) {
    int pos = blockIdx.x * 256 + threadIdx.x;
    bf16x8 z = {};
    *(bf16x8*)&dst[(size_t)pos * 8] = z;
}

// ---- pack weights: w[co][ci][tap] f32 -> wp[chunk16][tap9][half2][co256][8ci] bf16 ----
__global__ void pack_w(const float* __restrict__ w1, const float* __restrict__ w2,
                       __bf16* __restrict__ wp1, __bf16* __restrict__ wp2) {
    int id = blockIdx.x * 256 + threadIdx.x;         // < WP_EL
    const float* w = blockIdx.y ? w2 : w1;
    __bf16* wp = blockIdx.y ? wp2 : wp1;
    int j = id & 7; int t = id >> 3;
    int co = t & 255; t >>= 8;
    int half = t & 1; t >>= 1;
    int tap = t % 9; int chunk = t / 9;
    int ci = chunk * 16 + half * 8 + j;
    wp[id] = (__bf16)(w[((size_t)co * Cc + ci) * 9 + tap]);
}

// ---- fold BN params ----
__global__ void bn_prep(const float* g1, const float* b1, const float* m1, const float* v1,
                        const float* g2, const float* b2, const float* m2, const float* v2,
                        float* binv1, float* bbeta1, float* binv2, float* bbeta2) {
    int c = threadIdx.x;
    float i1 = g1[c] * rsqrtf(v1[c] + EPS);
    binv1[c] = i1; bbeta1[c] = b1[c] - m1[c] * i1;
    float i2 = g2[c] * rsqrtf(v2[c] + EPS);
    binv2[c] = i2; bbeta2[c] = b2[c] - m2[c] * i2;
}

template <bool C1>
__global__ __launch_bounds__(256, 2)
void conv_kern(const __bf16* __restrict__ pix,   // xm2 (conv1) or u2 (conv2), planar padded
               const __bf16* __restrict__ wp,    // packed weights
               const float* __restrict__ maskg,  // mask [B,HW]
               const float* __restrict__ vec,    // vector [B,C] (conv1 only)
               const float* __restrict__ binv, const float* __restrict__ bbeta,
               const float* __restrict__ xin,    // identity x NCHW f32 (conv2 only)
               void* __restrict__ dstv, int img0) {
    const int tid = threadIdx.x;
    const int lane = tid & 63, wave = tid >> 6;
    const int xlane = lane & 31, halfid = lane >> 5;
    const int band = blockIdx.x, cob = blockIdx.y, il = blockIdx.z;
    const int img = img0 + il;
    const int ybase = band * 4 + 2 * (wave >> 1);    // wave's 2 output rows
    const int c0 = cob * 128 + (wave & 1) * 64;      // wave's 64 co

    f32x16 acc[2][4];
    #pragma unroll
    for (int m = 0; m < 2; ++m)
        #pragma unroll
        for (int it = 0; it < 4; ++it)
            #pragma unroll
            for (int r = 0; r < 16; ++r) acc[m][it][r] = 0.f;

    const __bf16* pimg = pix + (size_t)il * IPS;

    for (int chunk = 0; chunk < 16; ++chunk) {
        const __bf16* wch = wp + (size_t)chunk * (9 * 2 * 256 * 8);
        const __bf16* pch = pimg + (size_t)(chunk * 2 + halfid) * PS;
        #pragma unroll
        for (int kh = 0; kh < 3; ++kh) {
            #pragma unroll
            for (int kw = 0; kw < 3; ++kw) {
                const int tap = kh * 3 + kw;
                bf16x8 wf[2], pf[4];
                #pragma unroll
                for (int m = 0; m < 2; ++m)
                    wf[m] = *(const bf16x8*)&wch[((size_t)(tap * 2 + halfid) * 256 +
                                                  c0 + m * 32 + xlane) * 8];
                #pragma unroll
                for (int it = 0; it < 4; ++it) {
                    int row = ybase + (it >> 1) + kh;         // padded row (y-1+kh -> +1)
                    int col = (it & 1) * 32 + kw + xlane;     // padded col (x-1+kw -> +1)
                    pf[it] = *(const bf16x8*)&pch[((size_t)row * PW + col) * 8];
                }
                #pragma unroll
                for (int m = 0; m < 2; ++m)
                    #pragma unroll
                    for (int it = 0; it < 4; ++it)
                        acc[m][it] = __builtin_amdgcn_mfma_f32_32x32x16_bf16(
                            wf[m], pf[it], acc[m][it], 0, 0, 0);
            }
        }
    }

    // ---- epilogue: D col(lane&31)=pixel x, row=(reg&3)+8*(reg>>2)+4*halfid=co ----
    float mv[4]; int yv[4], xv[4]; bool okv[4];
    #pragma unroll
    for (int it = 0; it < 4; ++it) {
        yv[it] = ybase + (it >> 1);
        xv[it] = (it & 1) * 32 + xlane;
        okv[it] = xv[it] < 56;
        mv[it] = okv[it] ? maskg[(size_t)img * HW + yv[it] * 56 + xv[it]] : 0.f;
    }

    if constexpr (C1) {
        __bf16* u2 = (__bf16*)dstv;
        #pragma unroll
        for (int m = 0; m < 2; ++m)
            #pragma unroll
            for (int rg = 0; rg < 4; ++rg) {
                const int c4 = c0 + m * 32 + rg * 8 + 4 * halfid;
                const float4 iv4 = *(const float4*)&binv[c4];
                const float4 bt4 = *(const float4*)&bbeta[c4];
                const float4 vv4 = *(const float4*)&vec[img * Cc + c4];
                const float ivv[4] = {iv4.x, iv4.y, iv4.z, iv4.w};
                const float btv[4] = {bt4.x, bt4.y, bt4.z, bt4.w};
                const float vvv[4] = {vv4.x, vv4.y, vv4.z, vv4.w};
                const int co8 = (c0 + m * 32) / 8 + rg;
                #pragma unroll
                for (int it = 0; it < 4; ++it) {
                    if (okv[it]) {
                        bf16x4 h;
                        #pragma unroll
                        for (int j = 0; j < 4; ++j) {
                            float o = fmaxf(fmaf(acc[m][it][rg * 4 + j], ivv[j], btv[j]), 0.f)
                                      * mv[it] * vvv[j];
                            h[j] = (__bf16)o;
                        }
                        size_t a = (((size_t)(il * 32 + co8) * PH + (yv[it] + 1)) * PW +
                                    (xv[it] + 1)) * 8 + 4 * halfid;
                        *(bf16x4*)&u2[a] = h;
                    }
                }
            }
    } else {
        float* outp = (float*)dstv;
        #pragma unroll
        for (int m = 0; m < 2; ++m)
            #pragma unroll
            for (int rg = 0; rg < 4; ++rg) {
                const int c4 = c0 + m * 32 + rg * 8 + 4 * halfid;
                const float4 iv4 = *(const float4*)&binv[c4];
                const float4 bt4 = *(const float4*)&bbeta[c4];
                const float ivv[4] = {iv4.x, iv4.y, iv4.z, iv4.w};
                const float btv[4] = {bt4.x, bt4.y, bt4.z, bt4.w};
                #pragma unroll
                for (int j = 0; j < 4; ++j) {
                    const size_t cbase = (size_t)(img * Cc + c4 + j) * HW;
                    #pragma unroll
                    for (int it = 0; it < 4; ++it) {
                        if (okv[it]) {
                            size_t oa = cbase + yv[it] * 56 + xv[it];
                            float o = fmaxf(
                                xin[oa] + mv[it] * fmaf(acc[m][it][rg * 4 + j], ivv[j], btv[j]),
                                0.f);
                            outp[oa] = o;
                        }
                    }
                }
            }
    }
}

extern "C" void kernel_launch(void* const* d_in, const int* in_sizes, int n_in,
                              void* d_out, int out_size, void* d_ws, size_t ws_size,
                              hipStream_t stream) {
    const float* x    = (const float*)d_in[0];
    const float* mask = (const float*)d_in[1];
    const float* md   = (const float*)d_in[2];
    const float* vec  = (const float*)d_in[3];
    const float* w1   = (const float*)d_in[4];
    const float* bn1g = (const float*)d_in[5];
    const float* bn1b = (const float*)d_in[6];
    const float* bn1m = (const float*)d_in[7];
    const float* bn1v = (const float*)d_in[8];
    const float* w2   = (const float*)d_in[9];
    const float* bn2g = (const float*)d_in[10];
    const float* bn2b = (const float*)d_in[11];
    const float* bn2m = (const float*)d_in[12];
    const float* bn2v = (const float*)d_in[13];
    float* out = (float*)d_out;

    // workspace: xm2 | u2 | wp1 | wp2 | bn params   (~65 MB total)
    __bf16* xm2 = (__bf16*)d_ws;
    __bf16* u2  = xm2 + (size_t)NG * IPS;
    __bf16* wp1 = u2 + (size_t)NG * IPS;
    __bf16* wp2 = wp1 + WP_EL;
    float* binv1  = (float*)(wp2 + WP_EL);
    float* bbeta1 = binv1 + 256;
    float* binv2  = bbeta1 + 256;
    float* bbeta2 = binv2 + 256;

    pack_w<<<dim3(WP_EL / 256, 2), dim3(256), 0, stream>>>(w1, w2, wp1, wp2);
    bn_prep<<<dim3(1), dim3(256), 0, stream>>>(bn1g, bn1b, bn1m, bn1v,
                                               bn2g, bn2b, bn2m, bn2v,
                                               binv1, bbeta1, binv2, bbeta2);

    for (int g = 0; g < 2; ++g) {
        const int img0 = g * NG;
        pack_xm2<<<dim3(PACK_POS / 256), dim3(256), 0, stream>>>(x, md, xm2, img0);
        zero_fill<<<dim3(PACK_POS / 256), dim3(256), 0, stream>>>(u2);
        dim3 grid(14, 2, NG);
        conv_kern<true><<<grid, dim3(256), 0, stream>>>(
            xm2, wp1, mask, vec, binv1, bbeta1, nullptr, u2, img0);
        conv_kern<false><<<grid, dim3(256), 0, stream>>>(
            u2, wp2, mask, nullptr, binv2, bbeta2, x, out, img0);
    }
}